// Round 5
// baseline (878.305 us; speedup 1.0000x reference)
//
#include <hip/hip_runtime.h>

#define NN 100000
#define CIN 500
#define KPAD 512
#define HID 256
#define COUT 50
#define NPADOUT 64
#define FPAD 64                        // padded feature-row length for x_k (128 B)

#define NBLK 256                       // edge-chunk blocks for P1/P2
#define CB 128                         // nodes per coarse bucket
#define NC ((NN + CB - 1) / CB)        // 782 coarse buckets
#define NCB (NC * NBLK)                // per-(bucket,block) counts
#define NCB2 (2 * NCB)                 // dst + src parts

#define SRCSH 13                       // src-chunk shift: 8192 nodes/chunk = 1.05 MB of rows
#define NCH ((NN + (1 << SRCSH) - 1) >> SRCSH)   // 13 chunks
#define NFINE (CB * NCH)               // 1664 (node, chunk) slots per coarse bucket

typedef __attribute__((ext_vector_type(8))) short short8;
typedef __attribute__((ext_vector_type(4))) float f32x4;

static __device__ __forceinline__ unsigned short f2bf(float f) {
  union { float f; unsigned u; } v; v.f = f;
  unsigned r = (v.u + 0x7fffu + ((v.u >> 16) & 1u)) >> 16;
  return (unsigned short)r;
}

static __device__ __forceinline__ int slotAt(const int* __restrict__ incl,
                                             const int* __restrict__ bpre, int g) {
  return g ? incl[g - 1] + bpre[(g - 1) >> 10] : 0;
}

// ---------------- build P1: coarse histograms (src & dst), LDS-privatized ----------------

__launch_bounds__(256)
__global__ void k_p1(const int* __restrict__ src, const int* __restrict__ dst,
                     int* __restrict__ blk_cnt, int E, int chunk) {
  __shared__ int bd[NC], bs[NC];
  int tid = threadIdx.x;
  for (int i = tid; i < NC; i += 256) { bd[i] = 0; bs[i] = 0; }
  __syncthreads();
  int e0 = blockIdx.x * chunk, e1 = min(E, e0 + chunk);
  for (int e = e0 + tid; e < e1; e += 256) {
    atomicAdd(&bd[dst[e] >> 7], 1);
    atomicAdd(&bs[src[e] >> 7], 1);
  }
  __syncthreads();
  for (int i = tid; i < NC; i += 256) {
    blk_cnt[i * NBLK + blockIdx.x] = bd[i];
    blk_cnt[NCB + i * NBLK + blockIdx.x] = bs[i];
  }
}

// ---------------- scan over NCB2 counts ----------------

__global__ void k_scan_a(const int* __restrict__ hist, int* __restrict__ incl,
                         int* __restrict__ bsum, int n) {
  __shared__ int ts[256];
  int tid = threadIdx.x;
  int base = blockIdx.x * 1024 + tid * 4;
  int a0 = 0, a1 = 0, a2 = 0, a3 = 0;
  if (base + 3 < n) {
    a0 = hist[base]; a1 = hist[base + 1]; a2 = hist[base + 2]; a3 = hist[base + 3];
  } else {
    if (base     < n) a0 = hist[base];
    if (base + 1 < n) a1 = hist[base + 1];
    if (base + 2 < n) a2 = hist[base + 2];
    if (base + 3 < n) a3 = hist[base + 3];
  }
  a1 += a0; a2 += a1; a3 += a2;
  ts[tid] = a3;
  __syncthreads();
  for (int o = 1; o < 256; o <<= 1) {
    int v = ts[tid];
    if (tid >= o) v += ts[tid - o];
    __syncthreads();
    ts[tid] = v;
    __syncthreads();
  }
  int ex = tid ? ts[tid - 1] : 0;
  if (base     < n) incl[base]     = a0 + ex;
  if (base + 1 < n) incl[base + 1] = a1 + ex;
  if (base + 2 < n) incl[base + 2] = a2 + ex;
  if (base + 3 < n) incl[base + 3] = a3 + ex;
  if (tid == 255) bsum[blockIdx.x] = ts[255];
}

__global__ void k_scan_b(const int* __restrict__ bsum, int* __restrict__ bpre, int nb) {
  __shared__ int s[512];
  int tid = threadIdx.x;
  s[tid] = (tid < nb) ? bsum[tid] : 0;
  __syncthreads();
  for (int o = 1; o < 512; o <<= 1) {
    int v = s[tid];
    if (tid >= o) v += s[tid - o];
    __syncthreads();
    s[tid] = v;
    __syncthreads();
  }
  if (tid < nb) bpre[tid] = tid ? s[tid - 1] : 0;
}

// ---------------- build P2: scatter edges into coarse buckets (no global atomics) ----------------

__launch_bounds__(256)
__global__ void k_p2(const int* __restrict__ src, const int* __restrict__ dst,
                     const int* __restrict__ incl, const int* __restrict__ bpre,
                     int* __restrict__ pkd, unsigned char* __restrict__ pks, int E, int chunk) {
  __shared__ int cd[NC], cs[NC];
  int tid = threadIdx.x;
  for (int i = tid; i < NC; i += 256) {
    cd[i] = slotAt(incl, bpre, i * NBLK + blockIdx.x);
    cs[i] = slotAt(incl, bpre, NCB + i * NBLK + blockIdx.x) - E;
  }
  __syncthreads();
  int e0 = blockIdx.x * chunk, e1 = min(E, e0 + chunk);
  for (int e = e0 + tid; e < e1; e += 256) {
    int s = src[e], d = dst[e];
    int pd = atomicAdd(&cd[d >> 7], 1);
    pkd[pd] = (s << 7) | (d & 127);
    int ps = atomicAdd(&cs[s >> 7], 1);
    pks[ps] = (unsigned char)(s & 127);
  }
}

// ---------------- build P3s: fine histogram of src -> dinv ----------------

__launch_bounds__(256)
__global__ void k_p3s(const int* __restrict__ incl, const int* __restrict__ bpre,
                      const unsigned char* __restrict__ pks, float* __restrict__ dinv, int E) {
  __shared__ int hist[CB];
  int b = blockIdx.x, tid = threadIdx.x;
  if (tid < CB) hist[tid] = 0;
  __syncthreads();
  int s0 = slotAt(incl, bpre, NCB + b * NBLK) - E;
  int s1 = slotAt(incl, bpre, NCB + (b + 1) * NBLK) - E;
  for (int e = s0 + tid; e < s1; e += 256) atomicAdd(&hist[pks[e]], 1);
  __syncthreads();
  if (tid < CB) {
    int node = b * CB + tid;
    if (node < NN) {
      int c = hist[tid];
      dinv[node] = c > 0 ? rsqrtf((float)c) : 0.f;
    }
  }
}

// ---------------- build P3d: fine sort by (dst, src-chunk) -> offs + (src,norm) CSR ----------
// R3 change (evidence: k_prop aggregate ~670us at 3.35 TB/s effective gather; 12.8 MB row
// table >> 4 MB per-XCD L2 -> ~31% L2 hit): each node's edge list is now ordered by src
// CHUNK (src>>13, 13 chunks of 1.05 MB). k_prop is untouched; it streams lists in
// ascending-src order, so the resident wave cohort sweeps src space in rough phase and
// gathers become L2-served. Keys are node-major (fine*NCH+chunk) so each node's segment
// stays contiguous and OFFS semantics are unchanged.

__launch_bounds__(256)
__global__ void k_p3d(const int* __restrict__ incl, const int* __restrict__ bpre,
                      const int* __restrict__ pkd, const float* __restrict__ dinv,
                      int* __restrict__ offs, int2* __restrict__ epk, int E) {
  __shared__ int ofs[NFINE];            // hist, then exclusive-scanned slot offsets
  __shared__ int part[256];
  int b = blockIdx.x, tid = threadIdx.x;
  for (int i = tid; i < NFINE; i += 256) ofs[i] = 0;
  __syncthreads();
  int s0 = slotAt(incl, bpre, b * NBLK);
  int s1 = slotAt(incl, bpre, (b + 1) * NBLK);
  for (int e = s0 + tid; e < s1; e += 256) {
    int pk = pkd[e];
    atomicAdd(&ofs[(pk & 127) * NCH + ((pk >> 7) >> SRCSH)], 1);
  }
  __syncthreads();
  // block-wide exclusive scan over ofs[0..NFINE): per-thread strip of 7 + scan of partials
  const int base0 = tid * 7;            // 256*7 = 1792 >= 1664
  int v[7];
  int run = 0;
#pragma unroll
  for (int q = 0; q < 7; q++) {
    int idx = base0 + q;
    int h = (idx < NFINE) ? ofs[idx] : 0;
    v[q] = run;
    run += h;
  }
  part[tid] = run;
  __syncthreads();
  for (int o = 1; o < 256; o <<= 1) {
    int t = part[tid];
    if (tid >= o) t += part[tid - o];
    __syncthreads();
    part[tid] = t;
    __syncthreads();
  }
  int ex = (tid ? part[tid - 1] : 0) + s0;
#pragma unroll
  for (int q = 0; q < 7; q++) {
    int idx = base0 + q;
    if (idx < NFINE) ofs[idx] = v[q] + ex;
  }
  __syncthreads();
  if (tid < CB) {
    int node = b * CB + tid;
    if (node < NN) offs[node] = ofs[tid * NCH];   // node segment starts at its chunk-0 slot
  }
  if (b == gridDim.x - 1 && tid == 0) offs[NN] = E;
  __syncthreads();                       // offs reads done before scatter mutates ofs
  for (int e = s0 + tid; e < s1; e += 256) {
    int pk = pkd[e];
    int fine = pk & 127, s = pk >> 7;
    int pos = atomicAdd(&ofs[fine * NCH + (s >> SRCSH)], 1);
    float nm = dinv[s] * dinv[b * CB + fine];
    epk[pos] = make_int2(s, __float_as_int(nm));
  }
}

// ---------------- weight transpose+convert (merged) ----------------

__global__ void k_wt(const float* __restrict__ W1, const float* __restrict__ W2,
                     unsigned short* __restrict__ W1T, unsigned short* __restrict__ W2T) {
  int idx = blockIdx.x * 256 + threadIdx.x;
  if (idx < HID * KPAD) {
    int n = idx >> 9, k = idx & 511;
    W1T[idx] = (k < CIN) ? f2bf(W1[(long)k * HID + n]) : (unsigned short)0;
  } else if (idx < HID * KPAD + NPADOUT * HID) {
    int i2 = idx - HID * KPAD;
    int n = i2 >> 8, k = i2 & 255;
    W2T[i2] = (n < COUT) ? f2bf(W2[(long)k * COUT + n]) : (unsigned short)0;
  }
}

// ---------------- fused MLP: h = relu(xW1+b1); out = hW2+b2 -> X0B(bf16) & HIDB ----------------
// R2: T14 async-STAGE split + LDS double-buffer (187 -> 152 us). Kept as verified.

__launch_bounds__(512)
__global__ void k_mlp(const float* __restrict__ X, const unsigned short* __restrict__ W1T,
                      const float* __restrict__ b1, const unsigned short* __restrict__ W2T,
                      const float* __restrict__ b2, const float* __restrict__ temp,
                      unsigned short* __restrict__ X0B, float* __restrict__ HIDB) {
  __shared__ unsigned short smem[2 * 15360];
  const int tid = threadIdx.x;
  const int lane = tid & 63, w = tid >> 6;
  const int wr = w >> 2, wc = w & 3;
  const int row0 = blockIdx.x * 128;
  f32x4 acc[4][4] = {};
  const int sr = tid >> 3, sc = tid & 7;
  const int br = tid >> 2, bc = tid & 3;

  float4 ra0, ra1;           // A-tile staging regs (fp32, converted at write time)
  uint4 rb0, rb1;            // B-tile staging regs (bf16 x8)

  auto load_regs = [&](int kk) {
    {
      int grow = row0 + sr;
      int gk = kk + sc * 4;
      if (grow < NN && gk < CIN)
        ra0 = *reinterpret_cast<const float4*>(&X[(long)grow * CIN + gk]);
      else { ra0.x = ra0.y = ra0.z = ra0.w = 0.f; }
    }
    {
      int grow = row0 + sr + 64;
      int gk = kk + sc * 4;
      if (grow < NN && gk < CIN)
        ra1 = *reinterpret_cast<const float4*>(&X[(long)grow * CIN + gk]);
      else { ra1.x = ra1.y = ra1.z = ra1.w = 0.f; }
    }
    rb0 = *reinterpret_cast<const uint4*>(&W1T[(long)br * KPAD + kk + bc * 8]);
    rb1 = *reinterpret_cast<const uint4*>(&W1T[(long)(br + 128) * KPAD + kk + bc * 8]);
  };

  auto write_lds = [&](unsigned short* As, unsigned short* Bs) {
    ushort4 v0, v1;
    v0.x = f2bf(ra0.x); v0.y = f2bf(ra0.y); v0.z = f2bf(ra0.z); v0.w = f2bf(ra0.w);
    v1.x = f2bf(ra1.x); v1.y = f2bf(ra1.y); v1.z = f2bf(ra1.z); v1.w = f2bf(ra1.w);
    *reinterpret_cast<ushort4*>(&As[sr * 40 + sc * 4]) = v0;
    *reinterpret_cast<ushort4*>(&As[(sr + 64) * 40 + sc * 4]) = v1;
    *reinterpret_cast<uint4*>(&Bs[br * 40 + bc * 8]) = rb0;
    *reinterpret_cast<uint4*>(&Bs[(br + 128) * 40 + bc * 8]) = rb1;
  };

  load_regs(0);
#pragma unroll 2
  for (int t = 0; t < 16; t++) {
    unsigned short* As = smem + (t & 1) * 15360;
    unsigned short* Bs = As + 128 * 40;
    write_lds(As, Bs);
    __syncthreads();
    if (t < 15) load_regs((t + 1) * 32);
    short8 af[4], bfr[4];
    const int koff = (lane >> 4) * 8;
#pragma unroll
    for (int i = 0; i < 4; i++)
      af[i] = *reinterpret_cast<const short8*>(&As[(wr * 64 + i * 16 + (lane & 15)) * 40 + koff]);
#pragma unroll
    for (int j = 0; j < 4; j++)
      bfr[j] = *reinterpret_cast<const short8*>(&Bs[(wc * 64 + j * 16 + (lane & 15)) * 40 + koff]);
#pragma unroll
    for (int i = 0; i < 4; i++)
#pragma unroll
      for (int j = 0; j < 4; j++)
        acc[i][j] = __builtin_amdgcn_mfma_f32_16x16x32_bf16(af[i], bfr[j], acc[i][j], 0, 0, 0);
  }

  // ---- epilogue: two 64-row phases through LDS, then h @ W2 ----
  unsigned short* Hs = smem;                    // 64 rows x 264 (stride pad)
  const float t0 = temp[0];
  const int rt = w >> 1;
  const int jh = w & 1;
#pragma unroll
  for (int ph = 0; ph < 2; ph++) {
    __syncthreads();
    if (wr == ph) {
#pragma unroll
      for (int i = 0; i < 4; i++) {
        int lr = i * 16 + (lane >> 4) * 4;
#pragma unroll
        for (int j = 0; j < 4; j++) {
          int col = wc * 64 + j * 16 + (lane & 15);
          float bv = b1[col];
#pragma unroll
          for (int r = 0; r < 4; r++) {
            float v = acc[i][j][r] + bv;
            v = v > 0.f ? v : 0.f;
            Hs[(lr + r) * 264 + col] = f2bf(v);
          }
        }
      }
    }
    __syncthreads();
    f32x4 acc2[2] = {};
    const int koff = (lane >> 4) * 8;
    for (int kk = 0; kk < HID; kk += 32) {
      short8 a = *reinterpret_cast<const short8*>(&Hs[(rt * 16 + (lane & 15)) * 264 + kk + koff]);
#pragma unroll
      for (int jj = 0; jj < 2; jj++) {
        int n = (jh * 2 + jj) * 16 + (lane & 15);
        short8 b = *reinterpret_cast<const short8*>(&W2T[n * HID + kk + koff]);
        acc2[jj] = __builtin_amdgcn_mfma_f32_16x16x32_bf16(a, b, acc2[jj], 0, 0, 0);
      }
    }
#pragma unroll
    for (int jj = 0; jj < 2; jj++) {
      int col = (jh * 2 + jj) * 16 + (lane & 15);
      float bv = (col < COUT) ? b2[col] : 0.f;
#pragma unroll
      for (int r = 0; r < 4; r++) {
        int row = row0 + ph * 64 + rt * 16 + (lane >> 4) * 4 + r;
        if (row < NN) {
          float v = acc2[jj][r] + bv;
          X0B[((long)row << 6) + col] = f2bf(v);
          if (col < COUT) HIDB[(long)row * COUT + col] = t0 * v;
        }
      }
    }
  }
}

// ---------------- propagation: bf16 padded rows (128 B aligned), 2 nodes/wave ----------------

__launch_bounds__(256)
__global__ void k_prop(const int* __restrict__ offs, const int2* __restrict__ epk,
                       const unsigned short* __restrict__ xin,
                       unsigned short* __restrict__ xout, float* __restrict__ hid,
                       const float* __restrict__ temp, int accidx) {
  int node = blockIdx.x * 8 + (threadIdx.x >> 5);
  if (node >= NN) return;
  int h = threadIdx.x & 31;
  int fp = h * 2;
  int s0 = offs[node], s1 = offs[node + 1];
  float a0 = 0.f, a1 = 0.f;
  int e = s0;
  for (; e + 7 < s1; e += 8) {
    int2 p[8];
#pragma unroll
    for (int q = 0; q < 8; q++) p[q] = epk[e + q];
    unsigned v[8];
#pragma unroll
    for (int q = 0; q < 8; q++)
      v[q] = *reinterpret_cast<const unsigned*>(&xin[((long)p[q].x << 6) + fp]);
#pragma unroll
    for (int q = 0; q < 8; q++) {
      float wq = __int_as_float(p[q].y);
      a0 += wq * __uint_as_float(v[q] << 16);
      a1 += wq * __uint_as_float(v[q] & 0xffff0000u);
    }
  }
  for (; e + 3 < s1; e += 4) {
    int2 p0 = epk[e], p1 = epk[e + 1], p2 = epk[e + 2], p3 = epk[e + 3];
    unsigned v0 = *reinterpret_cast<const unsigned*>(&xin[((long)p0.x << 6) + fp]);
    unsigned v1 = *reinterpret_cast<const unsigned*>(&xin[((long)p1.x << 6) + fp]);
    unsigned v2 = *reinterpret_cast<const unsigned*>(&xin[((long)p2.x << 6) + fp]);
    unsigned v3 = *reinterpret_cast<const unsigned*>(&xin[((long)p3.x << 6) + fp]);
    float w0 = __int_as_float(p0.y), w1 = __int_as_float(p1.y);
    float w2 = __int_as_float(p2.y), w3 = __int_as_float(p3.y);
    a0 += w0 * __uint_as_float(v0 << 16) + w1 * __uint_as_float(v1 << 16)
        + w2 * __uint_as_float(v2 << 16) + w3 * __uint_as_float(v3 << 16);
    a1 += w0 * __uint_as_float(v0 & 0xffff0000u) + w1 * __uint_as_float(v1 & 0xffff0000u)
        + w2 * __uint_as_float(v2 & 0xffff0000u) + w3 * __uint_as_float(v3 & 0xffff0000u);
  }
  for (; e < s1; e++) {
    int2 p0 = epk[e];
    float w0 = __int_as_float(p0.y);
    unsigned v0 = *reinterpret_cast<const unsigned*>(&xin[((long)p0.x << 6) + fp]);
    a0 += w0 * __uint_as_float(v0 << 16);
    a1 += w0 * __uint_as_float(v0 & 0xffff0000u);
  }
  if (fp < COUT) {
    unsigned pk = ((unsigned)f2bf(a1) << 16) | (unsigned)f2bf(a0);
    *reinterpret_cast<unsigned*>(&xout[((long)node << 6) + fp]) = pk;
    if (accidx >= 0) {
      float t = temp[accidx];
      float2* hp = reinterpret_cast<float2*>(&hid[(long)node * COUT + fp]);
      float2 o = *hp;
      o.x += t * a0; o.y += t * a1;
      *hp = o;
    }
  }
}

// ---------------- log_softmax ----------------

__launch_bounds__(256)
__global__ void k_lsm(const float* __restrict__ hid, float* __restrict__ out) {
  int node = blockIdx.x * 4 + (threadIdx.x >> 6);
  if (node >= NN) return;
  int f = threadIdx.x & 63;
  float v = (f < COUT) ? hid[(long)node * COUT + f] : -INFINITY;
  float m = v;
#pragma unroll
  for (int o = 32; o > 0; o >>= 1) m = fmaxf(m, __shfl_xor(m, o, 64));
  float ex = (f < COUT) ? expf(v - m) : 0.f;
  float s = ex;
#pragma unroll
  for (int o = 32; o > 0; o >>= 1) s += __shfl_xor(s, o, 64);
  if (f < COUT) out[(long)node * COUT + f] = (v - m) - logf(s);
}

// ---------------- launch ----------------

extern "C" void kernel_launch(void* const* d_in, const int* in_sizes, int n_in,
                              void* d_out, int out_size, void* d_ws, size_t ws_size,
                              hipStream_t stream) {
  const float* X  = (const float*)d_in[0];
  const int* EI   = (const int*)d_in[1];
  const float* W1 = (const float*)d_in[2];
  const float* B1 = (const float*)d_in[3];
  const float* W2 = (const float*)d_in[4];
  const float* B2 = (const float*)d_in[5];
  const float* TEMP = (const float*)d_in[6];
  const int E = in_sizes[1] / 2;
  const int* src = EI;
  const int* dst = EI + E;

  char* ws = (char*)d_ws;
  size_t off = 0;
  auto alloc = [&](size_t bytes) -> void* {
    off = (off + 511) & ~(size_t)511;
    void* p = ws + off;
    off += bytes;
    return p;
  };
  unsigned short* W1T = (unsigned short*)alloc((size_t)HID * KPAD * 2);
  unsigned short* W2T = (unsigned short*)alloc((size_t)NPADOUT * HID * 2);
  unsigned short* X0B = (unsigned short*)alloc((size_t)NN * FPAD * 2);
  unsigned short* X1B = (unsigned short*)alloc((size_t)NN * FPAD * 2);
  float* HIDB = (float*)alloc((size_t)NN * COUT * 4);
  float* DINV = (float*)alloc((size_t)NN * 4);
  int* OFFS   = (int*)alloc((size_t)(NN + 1) * 4);
  int* BLKC   = (int*)alloc((size_t)NCB2 * 4);
  int* INCL   = (int*)alloc((size_t)NCB2 * 4);
  int* BSUM   = (int*)alloc(512 * 4);
  int* BPRE   = (int*)alloc(512 * 4);
  int* PKD    = (int*)alloc((size_t)E * 4);
  unsigned char* PKS = (unsigned char*)alloc((size_t)E);
  int2* EPK   = (int2*)alloc((size_t)E * 8);

  const int chunk = (E + NBLK - 1) / NBLK;
  const int nsa = (NCB2 + 1023) / 1024;

  k_p1<<<NBLK, 256, 0, stream>>>(src, dst, BLKC, E, chunk);
  k_scan_a<<<nsa, 256, 0, stream>>>(BLKC, INCL, BSUM, NCB2);
  k_scan_b<<<1, 512, 0, stream>>>(BSUM, BPRE, nsa);
  k_p2<<<NBLK, 256, 0, stream>>>(src, dst, INCL, BPRE, PKD, PKS, E, chunk);
  k_p3s<<<NC, 256, 0, stream>>>(INCL, BPRE, PKS, DINV, E);
  k_p3d<<<NC, 256, 0, stream>>>(INCL, BPRE, PKD, DINV, OFFS, EPK, E);

  k_wt<<<(HID * KPAD + NPADOUT * HID + 255) / 256, 256, 0, stream>>>(W1, W2, W1T, W2T);

  k_mlp<<<(NN + 127) / 128, 512, 0, stream>>>(X, W1T, B1, W2T, B2, TEMP, X0B, HIDB);

  const int PB = (NN + 7) / 8;
  for (int k = 0; k < 5; k++) {
    k_prop<<<PB, 256, 0, stream>>>(OFFS, EPK, X0B, X1B, HIDB, TEMP, -1);
    k_prop<<<PB, 256, 0, stream>>>(OFFS, EPK, X1B, X0B, HIDB, TEMP, k + 1);
  }
  k_lsm<<<(NN + 3) / 4, 256, 0, stream>>>(HIDB, (float*)d_out);
}

// Round 6
// 863.873 us; speedup vs baseline: 1.0167x; 1.0167x over previous
//
#include <hip/hip_runtime.h>

#define NN 100000
#define CIN 500
#define KPAD 512
#define HID 256
#define COUT 50
#define NPADOUT 64
#define FPAD 64                        // padded feature-row length for x_k (128 B)

#define NBLK 256                       // edge-chunk blocks for P1/P2
#define CB 128                         // nodes per coarse bucket
#define NC ((NN + CB - 1) / CB)        // 782 coarse buckets
#define NCB (NC * NBLK)                // per-(bucket,block) counts
#define NCB2 (2 * NCB)                 // dst + src parts

typedef __attribute__((ext_vector_type(8))) short short8;
typedef __attribute__((ext_vector_type(4))) float f32x4;

static __device__ __forceinline__ unsigned short f2bf(float f) {
  union { float f; unsigned u; } v; v.f = f;
  unsigned r = (v.u + 0x7fffu + ((v.u >> 16) & 1u)) >> 16;
  return (unsigned short)r;
}

static __device__ __forceinline__ int slotAt(const int* __restrict__ incl,
                                             const int* __restrict__ bpre, int g) {
  return g ? incl[g - 1] + bpre[(g - 1) >> 10] : 0;
}

// ---------------- build P1: coarse histograms (src & dst), LDS-privatized ----------------

__launch_bounds__(256)
__global__ void k_p1(const int* __restrict__ src, const int* __restrict__ dst,
                     int* __restrict__ blk_cnt, int E, int chunk) {
  __shared__ int bd[NC], bs[NC];
  int tid = threadIdx.x;
  for (int i = tid; i < NC; i += 256) { bd[i] = 0; bs[i] = 0; }
  __syncthreads();
  int e0 = blockIdx.x * chunk, e1 = min(E, e0 + chunk);
  for (int e = e0 + tid; e < e1; e += 256) {
    atomicAdd(&bd[dst[e] >> 7], 1);
    atomicAdd(&bs[src[e] >> 7], 1);
  }
  __syncthreads();
  for (int i = tid; i < NC; i += 256) {
    blk_cnt[i * NBLK + blockIdx.x] = bd[i];
    blk_cnt[NCB + i * NBLK + blockIdx.x] = bs[i];
  }
}

// ---------------- scan over NCB2 counts ----------------

__global__ void k_scan_a(const int* __restrict__ hist, int* __restrict__ incl,
                         int* __restrict__ bsum, int n) {
  __shared__ int ts[256];
  int tid = threadIdx.x;
  int base = blockIdx.x * 1024 + tid * 4;
  int a0 = 0, a1 = 0, a2 = 0, a3 = 0;
  if (base + 3 < n) {
    a0 = hist[base]; a1 = hist[base + 1]; a2 = hist[base + 2]; a3 = hist[base + 3];
  } else {
    if (base     < n) a0 = hist[base];
    if (base + 1 < n) a1 = hist[base + 1];
    if (base + 2 < n) a2 = hist[base + 2];
    if (base + 3 < n) a3 = hist[base + 3];
  }
  a1 += a0; a2 += a1; a3 += a2;
  ts[tid] = a3;
  __syncthreads();
  for (int o = 1; o < 256; o <<= 1) {
    int v = ts[tid];
    if (tid >= o) v += ts[tid - o];
    __syncthreads();
    ts[tid] = v;
    __syncthreads();
  }
  int ex = tid ? ts[tid - 1] : 0;
  if (base     < n) incl[base]     = a0 + ex;
  if (base + 1 < n) incl[base + 1] = a1 + ex;
  if (base + 2 < n) incl[base + 2] = a2 + ex;
  if (base + 3 < n) incl[base + 3] = a3 + ex;
  if (tid == 255) bsum[blockIdx.x] = ts[255];
}

__global__ void k_scan_b(const int* __restrict__ bsum, int* __restrict__ bpre, int nb) {
  __shared__ int s[512];
  int tid = threadIdx.x;
  s[tid] = (tid < nb) ? bsum[tid] : 0;
  __syncthreads();
  for (int o = 1; o < 512; o <<= 1) {
    int v = s[tid];
    if (tid >= o) v += s[tid - o];
    __syncthreads();
    s[tid] = v;
    __syncthreads();
  }
  if (tid < nb) bpre[tid] = tid ? s[tid - 1] : 0;
}

// ---------------- build P2: scatter edges into coarse buckets (no global atomics) ----------------

__launch_bounds__(256)
__global__ void k_p2(const int* __restrict__ src, const int* __restrict__ dst,
                     const int* __restrict__ incl, const int* __restrict__ bpre,
                     int* __restrict__ pkd, unsigned char* __restrict__ pks, int E, int chunk) {
  __shared__ int cd[NC], cs[NC];
  int tid = threadIdx.x;
  for (int i = tid; i < NC; i += 256) {
    cd[i] = slotAt(incl, bpre, i * NBLK + blockIdx.x);
    cs[i] = slotAt(incl, bpre, NCB + i * NBLK + blockIdx.x) - E;
  }
  __syncthreads();
  int e0 = blockIdx.x * chunk, e1 = min(E, e0 + chunk);
  for (int e = e0 + tid; e < e1; e += 256) {
    int s = src[e], d = dst[e];
    int pd = atomicAdd(&cd[d >> 7], 1);
    pkd[pd] = (s << 7) | (d & 127);
    int ps = atomicAdd(&cs[s >> 7], 1);
    pks[ps] = (unsigned char)(s & 127);
  }
}

// ---------------- build P3s: fine histogram of src -> dinv ----------------

__launch_bounds__(256)
__global__ void k_p3s(const int* __restrict__ incl, const int* __restrict__ bpre,
                      const unsigned char* __restrict__ pks, float* __restrict__ dinv, int E) {
  __shared__ int hist[CB];
  int b = blockIdx.x, tid = threadIdx.x;
  if (tid < CB) hist[tid] = 0;
  __syncthreads();
  int s0 = slotAt(incl, bpre, NCB + b * NBLK) - E;
  int s1 = slotAt(incl, bpre, NCB + (b + 1) * NBLK) - E;
  for (int e = s0 + tid; e < s1; e += 256) atomicAdd(&hist[pks[e]], 1);
  __syncthreads();
  if (tid < CB) {
    int node = b * CB + tid;
    if (node < NN) {
      int c = hist[tid];
      dinv[node] = c > 0 ? rsqrtf((float)c) : 0.f;
    }
  }
}

// ---------------- build P3d: fine sort by dst -> offs + interleaved (src,norm) CSR ----------
// R5: reverted to the verified R2 form. The R3 src-chunk sub-sort measured NULL (878 vs
// 876 us): avg degree is 16, so a 16-edge list spread over 13 chunks has ~1.2 edges/chunk
// -- nothing to localize; the graph is random (no cross-list structure either).

__launch_bounds__(256)
__global__ void k_p3d(const int* __restrict__ incl, const int* __restrict__ bpre,
                      const int* __restrict__ pkd, const float* __restrict__ dinv,
                      int* __restrict__ offs, int2* __restrict__ epk, int E) {
  __shared__ int hist[CB], base[CB], cur[CB];
  int b = blockIdx.x, tid = threadIdx.x;
  if (tid < CB) hist[tid] = 0;
  __syncthreads();
  int s0 = slotAt(incl, bpre, b * NBLK);
  int s1 = slotAt(incl, bpre, (b + 1) * NBLK);
  for (int e = s0 + tid; e < s1; e += 256) atomicAdd(&hist[pkd[e] & 127], 1);
  __syncthreads();
  if (tid == 0) {
    int acc = s0;
    for (int i = 0; i < CB; i++) { base[i] = acc; cur[i] = acc; acc += hist[i]; }
  }
  __syncthreads();
  if (tid < CB) {
    int node = b * CB + tid;
    if (node < NN) offs[node] = base[tid];
  }
  if (b == gridDim.x - 1 && tid == 0) offs[NN] = E;
  for (int e = s0 + tid; e < s1; e += 256) {
    int pk = pkd[e];
    int fine = pk & 127, s = pk >> 7;
    int pos = atomicAdd(&cur[fine], 1);
    float nm = dinv[s] * dinv[b * CB + fine];
    epk[pos] = make_int2(s, __float_as_int(nm));
  }
}

// ---------------- weight transpose+convert (merged) ----------------

__global__ void k_wt(const float* __restrict__ W1, const float* __restrict__ W2,
                     unsigned short* __restrict__ W1T, unsigned short* __restrict__ W2T) {
  int idx = blockIdx.x * 256 + threadIdx.x;
  if (idx < HID * KPAD) {
    int n = idx >> 9, k = idx & 511;
    W1T[idx] = (k < CIN) ? f2bf(W1[(long)k * HID + n]) : (unsigned short)0;
  } else if (idx < HID * KPAD + NPADOUT * HID) {
    int i2 = idx - HID * KPAD;
    int n = i2 >> 8, k = i2 & 255;
    W2T[i2] = (n < COUT) ? f2bf(W2[(long)k * COUT + n]) : (unsigned short)0;
  }
}

// ---------------- fused MLP: h = relu(xW1+b1); out = hW2+b2 -> X0B(bf16) & HIDB ----------------
// R5 change (evidence: MfmaUtil 7.5%, VALUBusy 9%, HBM 12% -- all idle; X served by L3 at
// ~600-900cy but loads issued only ~1 MFMA-phase before the vmcnt-gated write_lds):
// distance-2 prefetch with TWO named register staging sets (static indexing, rule #20).
// Loads for tile t+2 issue at step t -> ~2 full step-times of latency cover; compiler
// emits counted vmcnt(4) since the other set's 4 loads stay outstanding (T3/T4, plain
// HIP). Barriers, LDS layout, MFMA order, numerics identical to the verified R2 kernel.

#define LOADS(ra0_, ra1_, rb0_, rb1_, kkc)                                        \
  {                                                                               \
    const int kk_ = (kkc);                                                        \
    bool okk = kk_ + sc * 4 <= 496;                                               \
    if (okA && okk) ra0_ = *reinterpret_cast<const float4*>(&X[xbaseA + kk_]);    \
    else { ra0_.x = ra0_.y = ra0_.z = ra0_.w = 0.f; }                             \
    if (okB && okk) ra1_ = *reinterpret_cast<const float4*>(&X[xbaseB + kk_]);    \
    else { ra1_.x = ra1_.y = ra1_.z = ra1_.w = 0.f; }                             \
    rb0_ = *reinterpret_cast<const uint4*>(&W1T[wbase0 + kk_]);                   \
    rb1_ = *reinterpret_cast<const uint4*>(&W1T[wbase1 + kk_]);                   \
  }

#define STORE_LDS(As_, Bs_, ra0_, ra1_, rb0_, rb1_)                               \
  {                                                                               \
    ushort4 v0, v1;                                                               \
    v0.x = f2bf(ra0_.x); v0.y = f2bf(ra0_.y); v0.z = f2bf(ra0_.z); v0.w = f2bf(ra0_.w); \
    v1.x = f2bf(ra1_.x); v1.y = f2bf(ra1_.y); v1.z = f2bf(ra1_.z); v1.w = f2bf(ra1_.w); \
    *reinterpret_cast<ushort4*>(&As_[sr * 40 + sc * 4]) = v0;                     \
    *reinterpret_cast<ushort4*>(&As_[(sr + 64) * 40 + sc * 4]) = v1;              \
    *reinterpret_cast<uint4*>(&Bs_[br * 40 + bc * 8]) = rb0_;                     \
    *reinterpret_cast<uint4*>(&Bs_[(br + 128) * 40 + bc * 8]) = rb1_;             \
  }

#define COMPUTE(As_, Bs_)                                                         \
  {                                                                               \
    short8 af[4], bfr[4];                                                         \
    const int koff = (lane >> 4) * 8;                                             \
    _Pragma("unroll")                                                             \
    for (int i = 0; i < 4; i++)                                                   \
      af[i] = *reinterpret_cast<const short8*>(&As_[(wr * 64 + i * 16 + (lane & 15)) * 40 + koff]); \
    _Pragma("unroll")                                                             \
    for (int j = 0; j < 4; j++)                                                   \
      bfr[j] = *reinterpret_cast<const short8*>(&Bs_[(wc * 64 + j * 16 + (lane & 15)) * 40 + koff]); \
    _Pragma("unroll")                                                             \
    for (int i = 0; i < 4; i++)                                                   \
      _Pragma("unroll")                                                           \
      for (int j = 0; j < 4; j++)                                                 \
        acc[i][j] = __builtin_amdgcn_mfma_f32_16x16x32_bf16(af[i], bfr[j], acc[i][j], 0, 0, 0); \
  }

__launch_bounds__(512)
__global__ void k_mlp(const float* __restrict__ X, const unsigned short* __restrict__ W1T,
                      const float* __restrict__ b1, const unsigned short* __restrict__ W2T,
                      const float* __restrict__ b2, const float* __restrict__ temp,
                      unsigned short* __restrict__ X0B, float* __restrict__ HIDB) {
  __shared__ unsigned short smem[2 * 15360];
  const int tid = threadIdx.x;
  const int lane = tid & 63, w = tid >> 6;
  const int wr = w >> 2, wc = w & 3;
  const int row0 = blockIdx.x * 128;
  f32x4 acc[4][4] = {};
  const int sr = tid >> 3, sc = tid & 7;
  const int br = tid >> 2, bc = tid & 3;

  // staging sets A (even K-steps) and B (odd K-steps)
  float4 raA0, raA1; uint4 rbA0, rbA1;
  float4 raB0, raB1; uint4 rbB0, rbB1;

  const int growA = row0 + sr;
  const int growB = row0 + sr + 64;
  const bool okA = growA < NN, okB = growB < NN;
  const long xbaseA = (long)growA * CIN + sc * 4;
  const long xbaseB = (long)growB * CIN + sc * 4;
  const long wbase0 = (long)br * KPAD + bc * 8;
  const long wbase1 = (long)(br + 128) * KPAD + bc * 8;

  LOADS(raA0, raA1, rbA0, rbA1, 0);
  LOADS(raB0, raB1, rbB0, rbB1, 32);

#pragma unroll
  for (int tt = 0; tt < 8; tt++) {
    const int kk0 = tt * 64;
    {   // even step: buf0, set A
      unsigned short* As = smem;
      unsigned short* Bs = smem + 128 * 40;
      STORE_LDS(As, Bs, raA0, raA1, rbA0, rbA1);   // waits set A only (vmcnt counted)
      __syncthreads();
      if (kk0 + 64 < KPAD) LOADS(raA0, raA1, rbA0, rbA1, kk0 + 64);  // tile t+2
      COMPUTE(As, Bs);
    }
    {   // odd step: buf1, set B
      unsigned short* As = smem + 15360;
      unsigned short* Bs = As + 128 * 40;
      STORE_LDS(As, Bs, raB0, raB1, rbB0, rbB1);
      __syncthreads();
      if (kk0 + 96 < KPAD) LOADS(raB0, raB1, rbB0, rbB1, kk0 + 96);  // tile t+2
      COMPUTE(As, Bs);
    }
  }

  // ---- epilogue: two 64-row phases through LDS, then h @ W2 ----
  unsigned short* Hs = smem;                    // 64 rows x 264 (stride pad)
  const float t0 = temp[0];
  const int rt = w >> 1;
  const int jh = w & 1;
#pragma unroll
  for (int ph = 0; ph < 2; ph++) {
    __syncthreads();
    if (wr == ph) {
#pragma unroll
      for (int i = 0; i < 4; i++) {
        int lr = i * 16 + (lane >> 4) * 4;
#pragma unroll
        for (int j = 0; j < 4; j++) {
          int col = wc * 64 + j * 16 + (lane & 15);
          float bv = b1[col];
#pragma unroll
          for (int r = 0; r < 4; r++) {
            float v = acc[i][j][r] + bv;
            v = v > 0.f ? v : 0.f;
            Hs[(lr + r) * 264 + col] = f2bf(v);
          }
        }
      }
    }
    __syncthreads();
    f32x4 acc2[2] = {};
    const int koff = (lane >> 4) * 8;
    for (int kk = 0; kk < HID; kk += 32) {
      short8 a = *reinterpret_cast<const short8*>(&Hs[(rt * 16 + (lane & 15)) * 264 + kk + koff]);
#pragma unroll
      for (int jj = 0; jj < 2; jj++) {
        int n = (jh * 2 + jj) * 16 + (lane & 15);
        short8 b = *reinterpret_cast<const short8*>(&W2T[n * HID + kk + koff]);
        acc2[jj] = __builtin_amdgcn_mfma_f32_16x16x32_bf16(a, b, acc2[jj], 0, 0, 0);
      }
    }
#pragma unroll
    for (int jj = 0; jj < 2; jj++) {
      int col = (jh * 2 + jj) * 16 + (lane & 15);
      float bv = (col < COUT) ? b2[col] : 0.f;
#pragma unroll
      for (int r = 0; r < 4; r++) {
        int row = row0 + ph * 64 + rt * 16 + (lane >> 4) * 4 + r;
        if (row < NN) {
          float v = acc2[jj][r] + bv;
          X0B[((long)row << 6) + col] = f2bf(v);
          if (col < COUT) HIDB[(long)row * COUT + col] = t0 * v;
        }
      }
    }
  }
}

// ---------------- propagation: bf16 padded rows (128 B aligned), 2 nodes/wave ----------------

__launch_bounds__(256)
__global__ void k_prop(const int* __restrict__ offs, const int2* __restrict__ epk,
                       const unsigned short* __restrict__ xin,
                       unsigned short* __restrict__ xout, float* __restrict__ hid,
                       const float* __restrict__ temp, int accidx) {
  int node = blockIdx.x * 8 + (threadIdx.x >> 5);
  if (node >= NN) return;
  int h = threadIdx.x & 31;
  int fp = h * 2;
  int s0 = offs[node], s1 = offs[node + 1];
  float a0 = 0.f, a1 = 0.f;
  int e = s0;
  for (; e + 7 < s1; e += 8) {
    int2 p[8];
#pragma unroll
    for (int q = 0; q < 8; q++) p[q] = epk[e + q];
    unsigned v[8];
#pragma unroll
    for (int q = 0; q < 8; q++)
      v[q] = *reinterpret_cast<const unsigned*>(&xin[((long)p[q].x << 6) + fp]);
#pragma unroll
    for (int q = 0; q < 8; q++) {
      float wq = __int_as_float(p[q].y);
      a0 += wq * __uint_as_float(v[q] << 16);
      a1 += wq * __uint_as_float(v[q] & 0xffff0000u);
    }
  }
  for (; e + 3 < s1; e += 4) {
    int2 p0 = epk[e], p1 = epk[e + 1], p2 = epk[e + 2], p3 = epk[e + 3];
    unsigned v0 = *reinterpret_cast<const unsigned*>(&xin[((long)p0.x << 6) + fp]);
    unsigned v1 = *reinterpret_cast<const unsigned*>(&xin[((long)p1.x << 6) + fp]);
    unsigned v2 = *reinterpret_cast<const unsigned*>(&xin[((long)p2.x << 6) + fp]);
    unsigned v3 = *reinterpret_cast<const unsigned*>(&xin[((long)p3.x << 6) + fp]);
    float w0 = __int_as_float(p0.y), w1 = __int_as_float(p1.y);
    float w2 = __int_as_float(p2.y), w3 = __int_as_float(p3.y);
    a0 += w0 * __uint_as_float(v0 << 16) + w1 * __uint_as_float(v1 << 16)
        + w2 * __uint_as_float(v2 << 16) + w3 * __uint_as_float(v3 << 16);
    a1 += w0 * __uint_as_float(v0 & 0xffff0000u) + w1 * __uint_as_float(v1 & 0xffff0000u)
        + w2 * __uint_as_float(v2 & 0xffff0000u) + w3 * __uint_as_float(v3 & 0xffff0000u);
  }
  for (; e < s1; e++) {
    int2 p0 = epk[e];
    float w0 = __int_as_float(p0.y);
    unsigned v0 = *reinterpret_cast<const unsigned*>(&xin[((long)p0.x << 6) + fp]);
    a0 += w0 * __uint_as_float(v0 << 16);
    a1 += w0 * __uint_as_float(v0 & 0xffff0000u);
  }
  if (fp < COUT) {
    unsigned pk = ((unsigned)f2bf(a1) << 16) | (unsigned)f2bf(a0);
    *reinterpret_cast<unsigned*>(&xout[((long)node << 6) + fp]) = pk;
    if (accidx >= 0) {
      float t = temp[accidx];
      float2* hp = reinterpret_cast<float2*>(&hid[(long)node * COUT + fp]);
      float2 o = *hp;
      o.x += t * a0; o.y += t * a1;
      *hp = o;
    }
  }
}

// ---------------- log_softmax ----------------

__launch_bounds__(256)
__global__ void k_lsm(const float* __restrict__ hid, float* __restrict__ out) {
  int node = blockIdx.x * 4 + (threadIdx.x >> 6);
  if (node >= NN) return;
  int f = threadIdx.x & 63;
  float v = (f < COUT) ? hid[(long)node * COUT + f] : -INFINITY;
  float m = v;
#pragma unroll
  for (int o = 32; o > 0; o >>= 1) m = fmaxf(m, __shfl_xor(m, o, 64));
  float ex = (f < COUT) ? expf(v - m) : 0.f;
  float s = ex;
#pragma unroll
  for (int o = 32; o > 0; o >>= 1) s += __shfl_xor(s, o, 64);
  if (f < COUT) out[(long)node * COUT + f] = (v - m) - logf(s);
}

// ---------------- launch ----------------

extern "C" void kernel_launch(void* const* d_in, const int* in_sizes, int n_in,
                              void* d_out, int out_size, void* d_ws, size_t ws_size,
                              hipStream_t stream) {
  const float* X  = (const float*)d_in[0];
  const int* EI   = (const int*)d_in[1];
  const float* W1 = (const float*)d_in[2];
  const float* B1 = (const float*)d_in[3];
  const float* W2 = (const float*)d_in[4];
  const float* B2 = (const float*)d_in[5];
  const float* TEMP = (const float*)d_in[6];
  const int E = in_sizes[1] / 2;
  const int* src = EI;
  const int* dst = EI + E;

  char* ws = (char*)d_ws;
  size_t off = 0;
  auto alloc = [&](size_t bytes) -> void* {
    off = (off + 511) & ~(size_t)511;
    void* p = ws + off;
    off += bytes;
    return p;
  };
  unsigned short* W1T = (unsigned short*)alloc((size_t)HID * KPAD * 2);
  unsigned short* W2T = (unsigned short*)alloc((size_t)NPADOUT * HID * 2);
  unsigned short* X0B = (unsigned short*)alloc((size_t)NN * FPAD * 2);
  unsigned short* X1B = (unsigned short*)alloc((size_t)NN * FPAD * 2);
  float* HIDB = (float*)alloc((size_t)NN * COUT * 4);
  float* DINV = (float*)alloc((size_t)NN * 4);
  int* OFFS   = (int*)alloc((size_t)(NN + 1) * 4);
  int* BLKC   = (int*)alloc((size_t)NCB2 * 4);
  int* INCL   = (int*)alloc((size_t)NCB2 * 4);
  int* BSUM   = (int*)alloc(512 * 4);
  int* BPRE   = (int*)alloc(512 * 4);
  int* PKD    = (int*)alloc((size_t)E * 4);
  unsigned char* PKS = (unsigned char*)alloc((size_t)E);
  int2* EPK   = (int2*)alloc((size_t)E * 8);

  const int chunk = (E + NBLK - 1) / NBLK;
  const int nsa = (NCB2 + 1023) / 1024;

  k_p1<<<NBLK, 256, 0, stream>>>(src, dst, BLKC, E, chunk);
  k_scan_a<<<nsa, 256, 0, stream>>>(BLKC, INCL, BSUM, NCB2);
  k_scan_b<<<1, 512, 0, stream>>>(BSUM, BPRE, nsa);
  k_p2<<<NBLK, 256, 0, stream>>>(src, dst, INCL, BPRE, PKD, PKS, E, chunk);
  k_p3s<<<NC, 256, 0, stream>>>(INCL, BPRE, PKS, DINV, E);
  k_p3d<<<NC, 256, 0, stream>>>(INCL, BPRE, PKD, DINV, OFFS, EPK, E);

  k_wt<<<(HID * KPAD + NPADOUT * HID + 255) / 256, 256, 0, stream>>>(W1, W2, W1T, W2T);

  k_mlp<<<(NN + 127) / 128, 512, 0, stream>>>(X, W1T, B1, W2T, B2, TEMP, X0B, HIDB);

  const int PB = (NN + 7) / 8;
  for (int k = 0; k < 5; k++) {
    k_prop<<<PB, 256, 0, stream>>>(OFFS, EPK, X0B, X1B, HIDB, TEMP, -1);
    k_prop<<<PB, 256, 0, stream>>>(OFFS, EPK, X1B, X0B, HIDB, TEMP, k + 1);
  }
  k_lsm<<<(NN + 3) / 4, 256, 0, stream>>>(HIDB, (float*)d_out);
}

// Round 7
// 825.683 us; speedup vs baseline: 1.0637x; 1.0463x over previous
//
#include <hip/hip_runtime.h>

#define NN 100000
#define CIN 500
#define KPAD 512
#define HID 256
#define COUT 50
#define NPADOUT 64
#define FPAD 64                        // padded feature-row length for x_k (128 B)

#define NBLK 256                       // edge-chunk blocks for P1/P2
#define CB 128                         // nodes per coarse bucket
#define NC ((NN + CB - 1) / CB)        // 782 coarse buckets
#define NCB (NC * NBLK)                // per-(bucket,block) counts
#define NCB2 (2 * NCB)                 // dst + src parts

typedef __attribute__((ext_vector_type(8))) short short8;
typedef __attribute__((ext_vector_type(4))) float f32x4;

static __device__ __forceinline__ unsigned short f2bf(float f) {
  union { float f; unsigned u; } v; v.f = f;
  unsigned r = (v.u + 0x7fffu + ((v.u >> 16) & 1u)) >> 16;
  return (unsigned short)r;
}

static __device__ __forceinline__ int slotAt(const int* __restrict__ incl,
                                             const int* __restrict__ bpre, int g) {
  return g ? incl[g - 1] + bpre[(g - 1) >> 10] : 0;
}

// ---------------- build P1: coarse histograms (src & dst), LDS-privatized ----------------

__launch_bounds__(256)
__global__ void k_p1(const int* __restrict__ src, const int* __restrict__ dst,
                     int* __restrict__ blk_cnt, int E, int chunk) {
  __shared__ int bd[NC], bs[NC];
  int tid = threadIdx.x;
  for (int i = tid; i < NC; i += 256) { bd[i] = 0; bs[i] = 0; }
  __syncthreads();
  int e0 = blockIdx.x * chunk, e1 = min(E, e0 + chunk);
  for (int e = e0 + tid; e < e1; e += 256) {
    atomicAdd(&bd[dst[e] >> 7], 1);
    atomicAdd(&bs[src[e] >> 7], 1);
  }
  __syncthreads();
  for (int i = tid; i < NC; i += 256) {
    blk_cnt[i * NBLK + blockIdx.x] = bd[i];
    blk_cnt[NCB + i * NBLK + blockIdx.x] = bs[i];
  }
}

// ---------------- scan over NCB2 counts ----------------

__global__ void k_scan_a(const int* __restrict__ hist, int* __restrict__ incl,
                         int* __restrict__ bsum, int n) {
  __shared__ int ts[256];
  int tid = threadIdx.x;
  int base = blockIdx.x * 1024 + tid * 4;
  int a0 = 0, a1 = 0, a2 = 0, a3 = 0;
  if (base + 3 < n) {
    a0 = hist[base]; a1 = hist[base + 1]; a2 = hist[base + 2]; a3 = hist[base + 3];
  } else {
    if (base     < n) a0 = hist[base];
    if (base + 1 < n) a1 = hist[base + 1];
    if (base + 2 < n) a2 = hist[base + 2];
    if (base + 3 < n) a3 = hist[base + 3];
  }
  a1 += a0; a2 += a1; a3 += a2;
  ts[tid] = a3;
  __syncthreads();
  for (int o = 1; o < 256; o <<= 1) {
    int v = ts[tid];
    if (tid >= o) v += ts[tid - o];
    __syncthreads();
    ts[tid] = v;
    __syncthreads();
  }
  int ex = tid ? ts[tid - 1] : 0;
  if (base     < n) incl[base]     = a0 + ex;
  if (base + 1 < n) incl[base + 1] = a1 + ex;
  if (base + 2 < n) incl[base + 2] = a2 + ex;
  if (base + 3 < n) incl[base + 3] = a3 + ex;
  if (tid == 255) bsum[blockIdx.x] = ts[255];
}

__global__ void k_scan_b(const int* __restrict__ bsum, int* __restrict__ bpre, int nb) {
  __shared__ int s[512];
  int tid = threadIdx.x;
  s[tid] = (tid < nb) ? bsum[tid] : 0;
  __syncthreads();
  for (int o = 1; o < 512; o <<= 1) {
    int v = s[tid];
    if (tid >= o) v += s[tid - o];
    __syncthreads();
    s[tid] = v;
    __syncthreads();
  }
  if (tid < nb) bpre[tid] = tid ? s[tid - 1] : 0;
}

// ---------------- build P2: scatter edges into coarse buckets (no global atomics) ----------------

__launch_bounds__(256)
__global__ void k_p2(const int* __restrict__ src, const int* __restrict__ dst,
                     const int* __restrict__ incl, const int* __restrict__ bpre,
                     int* __restrict__ pkd, unsigned char* __restrict__ pks, int E, int chunk) {
  __shared__ int cd[NC], cs[NC];
  int tid = threadIdx.x;
  for (int i = tid; i < NC; i += 256) {
    cd[i] = slotAt(incl, bpre, i * NBLK + blockIdx.x);
    cs[i] = slotAt(incl, bpre, NCB + i * NBLK + blockIdx.x) - E;
  }
  __syncthreads();
  int e0 = blockIdx.x * chunk, e1 = min(E, e0 + chunk);
  for (int e = e0 + tid; e < e1; e += 256) {
    int s = src[e], d = dst[e];
    int pd = atomicAdd(&cd[d >> 7], 1);
    pkd[pd] = (s << 7) | (d & 127);
    int ps = atomicAdd(&cs[s >> 7], 1);
    pks[ps] = (unsigned char)(s & 127);
  }
}

// ---------------- build P3s: fine histogram of src -> dinv ----------------

__launch_bounds__(256)
__global__ void k_p3s(const int* __restrict__ incl, const int* __restrict__ bpre,
                      const unsigned char* __restrict__ pks, float* __restrict__ dinv, int E) {
  __shared__ int hist[CB];
  int b = blockIdx.x, tid = threadIdx.x;
  if (tid < CB) hist[tid] = 0;
  __syncthreads();
  int s0 = slotAt(incl, bpre, NCB + b * NBLK) - E;
  int s1 = slotAt(incl, bpre, NCB + (b + 1) * NBLK) - E;
  for (int e = s0 + tid; e < s1; e += 256) atomicAdd(&hist[pks[e]], 1);
  __syncthreads();
  if (tid < CB) {
    int node = b * CB + tid;
    if (node < NN) {
      int c = hist[tid];
      dinv[node] = c > 0 ? rsqrtf((float)c) : 0.f;
    }
  }
}

// ---------------- build P3d: fine sort by dst -> offs + interleaved (src,norm) CSR ----------

__launch_bounds__(256)
__global__ void k_p3d(const int* __restrict__ incl, const int* __restrict__ bpre,
                      const int* __restrict__ pkd, const float* __restrict__ dinv,
                      int* __restrict__ offs, int2* __restrict__ epk, int E) {
  __shared__ int hist[CB], base[CB], cur[CB];
  int b = blockIdx.x, tid = threadIdx.x;
  if (tid < CB) hist[tid] = 0;
  __syncthreads();
  int s0 = slotAt(incl, bpre, b * NBLK);
  int s1 = slotAt(incl, bpre, (b + 1) * NBLK);
  for (int e = s0 + tid; e < s1; e += 256) atomicAdd(&hist[pkd[e] & 127], 1);
  __syncthreads();
  if (tid == 0) {
    int acc = s0;
    for (int i = 0; i < CB; i++) { base[i] = acc; cur[i] = acc; acc += hist[i]; }
  }
  __syncthreads();
  if (tid < CB) {
    int node = b * CB + tid;
    if (node < NN) offs[node] = base[tid];
  }
  if (b == gridDim.x - 1 && tid == 0) offs[NN] = E;
  for (int e = s0 + tid; e < s1; e += 256) {
    int pk = pkd[e];
    int fine = pk & 127, s = pk >> 7;
    int pos = atomicAdd(&cur[fine], 1);
    float nm = dinv[s] * dinv[b * CB + fine];
    epk[pos] = make_int2(s, __float_as_int(nm));
  }
}

// ---------------- weight transpose+convert (merged) ----------------

__global__ void k_wt(const float* __restrict__ W1, const float* __restrict__ W2,
                     unsigned short* __restrict__ W1T, unsigned short* __restrict__ W2T) {
  int idx = blockIdx.x * 256 + threadIdx.x;
  if (idx < HID * KPAD) {
    int n = idx >> 9, k = idx & 511;
    W1T[idx] = (k < CIN) ? f2bf(W1[(long)k * HID + n]) : (unsigned short)0;
  } else if (idx < HID * KPAD + NPADOUT * HID) {
    int i2 = idx - HID * KPAD;
    int n = i2 >> 8, k = i2 & 255;
    W2T[i2] = (n < COUT) ? f2bf(W2[(long)k * COUT + n]) : (unsigned short)0;
  }
}

// ---------------- fused MLP (R5 distance-2 prefetch, verified 142us) ----------------

#define LOADS(ra0_, ra1_, rb0_, rb1_, kkc)                                        \
  {                                                                               \
    const int kk_ = (kkc);                                                        \
    bool okk = kk_ + sc * 4 <= 496;                                               \
    if (okA && okk) ra0_ = *reinterpret_cast<const float4*>(&X[xbaseA + kk_]);    \
    else { ra0_.x = ra0_.y = ra0_.z = ra0_.w = 0.f; }                             \
    if (okB && okk) ra1_ = *reinterpret_cast<const float4*>(&X[xbaseB + kk_]);    \
    else { ra1_.x = ra1_.y = ra1_.z = ra1_.w = 0.f; }                             \
    rb0_ = *reinterpret_cast<const uint4*>(&W1T[wbase0 + kk_]);                   \
    rb1_ = *reinterpret_cast<const uint4*>(&W1T[wbase1 + kk_]);                   \
  }

#define STORE_LDS(As_, Bs_, ra0_, ra1_, rb0_, rb1_)                               \
  {                                                                               \
    ushort4 v0, v1;                                                               \
    v0.x = f2bf(ra0_.x); v0.y = f2bf(ra0_.y); v0.z = f2bf(ra0_.z); v0.w = f2bf(ra0_.w); \
    v1.x = f2bf(ra1_.x); v1.y = f2bf(ra1_.y); v1.z = f2bf(ra1_.z); v1.w = f2bf(ra1_.w); \
    *reinterpret_cast<ushort4*>(&As_[sr * 40 + sc * 4]) = v0;                     \
    *reinterpret_cast<ushort4*>(&As_[(sr + 64) * 40 + sc * 4]) = v1;              \
    *reinterpret_cast<uint4*>(&Bs_[br * 40 + bc * 8]) = rb0_;                     \
    *reinterpret_cast<uint4*>(&Bs_[(br + 128) * 40 + bc * 8]) = rb1_;             \
  }

#define COMPUTE(As_, Bs_)                                                         \
  {                                                                               \
    short8 af[4], bfr[4];                                                         \
    const int koff = (lane >> 4) * 8;                                             \
    _Pragma("unroll")                                                             \
    for (int i = 0; i < 4; i++)                                                   \
      af[i] = *reinterpret_cast<const short8*>(&As_[(wr * 64 + i * 16 + (lane & 15)) * 40 + koff]); \
    _Pragma("unroll")                                                             \
    for (int j = 0; j < 4; j++)                                                   \
      bfr[j] = *reinterpret_cast<const short8*>(&Bs_[(wc * 64 + j * 16 + (lane & 15)) * 40 + koff]); \
    _Pragma("unroll")                                                             \
    for (int i = 0; i < 4; i++)                                                   \
      _Pragma("unroll")                                                           \
      for (int j = 0; j < 4; j++)                                                 \
        acc[i][j] = __builtin_amdgcn_mfma_f32_16x16x32_bf16(af[i], bfr[j], acc[i][j], 0, 0, 0); \
  }

__launch_bounds__(512)
__global__ void k_mlp(const float* __restrict__ X, const unsigned short* __restrict__ W1T,
                      const float* __restrict__ b1, const unsigned short* __restrict__ W2T,
                      const float* __restrict__ b2, const float* __restrict__ temp,
                      unsigned short* __restrict__ X0B, float* __restrict__ HIDB) {
  __shared__ unsigned short smem[2 * 15360];
  const int tid = threadIdx.x;
  const int lane = tid & 63, w = tid >> 6;
  const int wr = w >> 2, wc = w & 3;
  const int row0 = blockIdx.x * 128;
  f32x4 acc[4][4] = {};
  const int sr = tid >> 3, sc = tid & 7;
  const int br = tid >> 2, bc = tid & 3;

  float4 raA0, raA1; uint4 rbA0, rbA1;
  float4 raB0, raB1; uint4 rbB0, rbB1;

  const int growA = row0 + sr;
  const int growB = row0 + sr + 64;
  const bool okA = growA < NN, okB = growB < NN;
  const long xbaseA = (long)growA * CIN + sc * 4;
  const long xbaseB = (long)growB * CIN + sc * 4;
  const long wbase0 = (long)br * KPAD + bc * 8;
  const long wbase1 = (long)(br + 128) * KPAD + bc * 8;

  LOADS(raA0, raA1, rbA0, rbA1, 0);
  LOADS(raB0, raB1, rbB0, rbB1, 32);

#pragma unroll
  for (int tt = 0; tt < 8; tt++) {
    const int kk0 = tt * 64;
    {   // even step: buf0, set A
      unsigned short* As = smem;
      unsigned short* Bs = smem + 128 * 40;
      STORE_LDS(As, Bs, raA0, raA1, rbA0, rbA1);
      __syncthreads();
      if (kk0 + 64 < KPAD) LOADS(raA0, raA1, rbA0, rbA1, kk0 + 64);
      COMPUTE(As, Bs);
    }
    {   // odd step: buf1, set B
      unsigned short* As = smem + 15360;
      unsigned short* Bs = As + 128 * 40;
      STORE_LDS(As, Bs, raB0, raB1, rbB0, rbB1);
      __syncthreads();
      if (kk0 + 96 < KPAD) LOADS(raB0, raB1, rbB0, rbB1, kk0 + 96);
      COMPUTE(As, Bs);
    }
  }

  // ---- epilogue: two 64-row phases through LDS, then h @ W2 ----
  unsigned short* Hs = smem;                    // 64 rows x 264 (stride pad)
  const float t0 = temp[0];
  const int rt = w >> 1;
  const int jh = w & 1;
#pragma unroll
  for (int ph = 0; ph < 2; ph++) {
    __syncthreads();
    if (wr == ph) {
#pragma unroll
      for (int i = 0; i < 4; i++) {
        int lr = i * 16 + (lane >> 4) * 4;
#pragma unroll
        for (int j = 0; j < 4; j++) {
          int col = wc * 64 + j * 16 + (lane & 15);
          float bv = b1[col];
#pragma unroll
          for (int r = 0; r < 4; r++) {
            float v = acc[i][j][r] + bv;
            v = v > 0.f ? v : 0.f;
            Hs[(lr + r) * 264 + col] = f2bf(v);
          }
        }
      }
    }
    __syncthreads();
    f32x4 acc2[2] = {};
    const int koff = (lane >> 4) * 8;
    for (int kk = 0; kk < HID; kk += 32) {
      short8 a = *reinterpret_cast<const short8*>(&Hs[(rt * 16 + (lane & 15)) * 264 + kk + koff]);
#pragma unroll
      for (int jj = 0; jj < 2; jj++) {
        int n = (jh * 2 + jj) * 16 + (lane & 15);
        short8 b = *reinterpret_cast<const short8*>(&W2T[n * HID + kk + koff]);
        acc2[jj] = __builtin_amdgcn_mfma_f32_16x16x32_bf16(a, b, acc2[jj], 0, 0, 0);
      }
    }
#pragma unroll
    for (int jj = 0; jj < 2; jj++) {
      int col = (jh * 2 + jj) * 16 + (lane & 15);
      float bv = (col < COUT) ? b2[col] : 0.f;
#pragma unroll
      for (int r = 0; r < 4; r++) {
        int row = row0 + ph * 64 + rt * 16 + (lane >> 4) * 4 + r;
        if (row < NN) {
          float v = acc2[jj][r] + bv;
          X0B[((long)row << 6) + col] = f2bf(v);
          if (col < COUT) HIDB[(long)row * COUT + col] = t0 * v;
        }
      }
    }
  }
}

// ---------------- propagation: 4 nodes/wave, 16 lanes/node, uint2 (8 B) per lane ----------
// R6 change (evidence: k_prop aggregate 668us = 3.07 TB/s gather from a 12.8 MB table;
// Little's law gives only ~57 lines in flight per CU -> concurrency/duty-bound, not a BW
// wall): double the independent gather streams per wave. Lane h (0..15) of each 16-lane
// group handles 4 features via one dwordx2 gather; per-edge coalescing unchanged (16
// lanes x 8 B = one 128-B line). Edge order and per-feature FMA order identical to the
// verified 2-node version -> bitwise-identical output.

__launch_bounds__(256)
__global__ void k_prop(const int* __restrict__ offs, const int2* __restrict__ epk,
                       const unsigned short* __restrict__ xin,
                       unsigned short* __restrict__ xout, float* __restrict__ hid,
                       const float* __restrict__ temp, int accidx) {
  int node = blockIdx.x * 16 + (threadIdx.x >> 4);
  if (node >= NN) return;
  int h = threadIdx.x & 15;
  int fp = h * 4;                       // first of 4 features (shorts) this lane owns
  int s0 = offs[node], s1 = offs[node + 1];
  float a0 = 0.f, a1 = 0.f, a2 = 0.f, a3 = 0.f;
  int e = s0;
  for (; e + 7 < s1; e += 8) {
    int2 p[8];
#pragma unroll
    for (int q = 0; q < 8; q++) p[q] = epk[e + q];
    uint2 v[8];
#pragma unroll
    for (int q = 0; q < 8; q++)
      v[q] = *reinterpret_cast<const uint2*>(&xin[((long)p[q].x << 6) + fp]);
#pragma unroll
    for (int q = 0; q < 8; q++) {
      float wq = __int_as_float(p[q].y);
      a0 += wq * __uint_as_float(v[q].x << 16);
      a1 += wq * __uint_as_float(v[q].x & 0xffff0000u);
      a2 += wq * __uint_as_float(v[q].y << 16);
      a3 += wq * __uint_as_float(v[q].y & 0xffff0000u);
    }
  }
  for (; e + 3 < s1; e += 4) {
    int2 p0 = epk[e], p1 = epk[e + 1], p2 = epk[e + 2], p3 = epk[e + 3];
    uint2 v0 = *reinterpret_cast<const uint2*>(&xin[((long)p0.x << 6) + fp]);
    uint2 v1 = *reinterpret_cast<const uint2*>(&xin[((long)p1.x << 6) + fp]);
    uint2 v2 = *reinterpret_cast<const uint2*>(&xin[((long)p2.x << 6) + fp]);
    uint2 v3 = *reinterpret_cast<const uint2*>(&xin[((long)p3.x << 6) + fp]);
    float w0 = __int_as_float(p0.y), w1 = __int_as_float(p1.y);
    float w2 = __int_as_float(p2.y), w3 = __int_as_float(p3.y);
    a0 += w0 * __uint_as_float(v0.x << 16) + w1 * __uint_as_float(v1.x << 16)
        + w2 * __uint_as_float(v2.x << 16) + w3 * __uint_as_float(v3.x << 16);
    a1 += w0 * __uint_as_float(v0.x & 0xffff0000u) + w1 * __uint_as_float(v1.x & 0xffff0000u)
        + w2 * __uint_as_float(v2.x & 0xffff0000u) + w3 * __uint_as_float(v3.x & 0xffff0000u);
    a2 += w0 * __uint_as_float(v0.y << 16) + w1 * __uint_as_float(v1.y << 16)
        + w2 * __uint_as_float(v2.y << 16) + w3 * __uint_as_float(v3.y << 16);
    a3 += w0 * __uint_as_float(v0.y & 0xffff0000u) + w1 * __uint_as_float(v1.y & 0xffff0000u)
        + w2 * __uint_as_float(v2.y & 0xffff0000u) + w3 * __uint_as_float(v3.y & 0xffff0000u);
  }
  for (; e < s1; e++) {
    int2 p0 = epk[e];
    float w0 = __int_as_float(p0.y);
    uint2 v0 = *reinterpret_cast<const uint2*>(&xin[((long)p0.x << 6) + fp]);
    a0 += w0 * __uint_as_float(v0.x << 16);
    a1 += w0 * __uint_as_float(v0.x & 0xffff0000u);
    a2 += w0 * __uint_as_float(v0.y << 16);
    a3 += w0 * __uint_as_float(v0.y & 0xffff0000u);
  }
  // features this lane owns: fp, fp+1 (dword d0) and fp+2, fp+3 (dword d1); COUT=50
  unsigned d0 = ((unsigned)f2bf(a1) << 16) | (unsigned)f2bf(a0);
  unsigned d1 = ((unsigned)f2bf(a3) << 16) | (unsigned)f2bf(a2);
  if (h <= 11) {        // features <= 47: both dwords
    uint2 pk2; pk2.x = d0; pk2.y = d1;
    *reinterpret_cast<uint2*>(&xout[((long)node << 6) + fp]) = pk2;
  } else if (h == 12) { // features 48,49 in d0; 50,51 are pad
    *reinterpret_cast<unsigned*>(&xout[((long)node << 6) + fp]) = d0;
  }
  if (accidx >= 0) {
    float t = temp[accidx];
    if (h <= 11) {
      float2* hp0 = reinterpret_cast<float2*>(&hid[(long)node * COUT + fp]);
      float2 o0 = *hp0;
      o0.x += t * a0; o0.y += t * a1;
      *hp0 = o0;
      float2* hp1 = reinterpret_cast<float2*>(&hid[(long)node * COUT + fp + 2]);
      float2 o1 = *hp1;
      o1.x += t * a2; o1.y += t * a3;
      *hp1 = o1;
    } else if (h == 12) {
      float2* hp0 = reinterpret_cast<float2*>(&hid[(long)node * COUT + fp]);
      float2 o0 = *hp0;
      o0.x += t * a0; o0.y += t * a1;
      *hp0 = o0;
    }
  }
}

// ---------------- log_softmax ----------------

__launch_bounds__(256)
__global__ void k_lsm(const float* __restrict__ hid, float* __restrict__ out) {
  int node = blockIdx.x * 4 + (threadIdx.x >> 6);
  if (node >= NN) return;
  int f = threadIdx.x & 63;
  float v = (f < COUT) ? hid[(long)node * COUT + f] : -INFINITY;
  float m = v;
#pragma unroll
  for (int o = 32; o > 0; o >>= 1) m = fmaxf(m, __shfl_xor(m, o, 64));
  float ex = (f < COUT) ? expf(v - m) : 0.f;
  float s = ex;
#pragma unroll
  for (int o = 32; o > 0; o >>= 1) s += __shfl_xor(s, o, 64);
  if (f < COUT) out[(long)node * COUT + f] = (v - m) - logf(s);
}

// ---------------- launch ----------------

extern "C" void kernel_launch(void* const* d_in, const int* in_sizes, int n_in,
                              void* d_out, int out_size, void* d_ws, size_t ws_size,
                              hipStream_t stream) {
  const float* X  = (const float*)d_in[0];
  const int* EI   = (const int*)d_in[1];
  const float* W1 = (const float*)d_in[2];
  const float* B1 = (const float*)d_in[3];
  const float* W2 = (const float*)d_in[4];
  const float* B2 = (const float*)d_in[5];
  const float* TEMP = (const float*)d_in[6];
  const int E = in_sizes[1] / 2;
  const int* src = EI;
  const int* dst = EI + E;

  char* ws = (char*)d_ws;
  size_t off = 0;
  auto alloc = [&](size_t bytes) -> void* {
    off = (off + 511) & ~(size_t)511;
    void* p = ws + off;
    off += bytes;
    return p;
  };
  unsigned short* W1T = (unsigned short*)alloc((size_t)HID * KPAD * 2);
  unsigned short* W2T = (unsigned short*)alloc((size_t)NPADOUT * HID * 2);
  unsigned short* X0B = (unsigned short*)alloc((size_t)NN * FPAD * 2);
  unsigned short* X1B = (unsigned short*)alloc((size_t)NN * FPAD * 2);
  float* HIDB = (float*)alloc((size_t)NN * COUT * 4);
  float* DINV = (float*)alloc((size_t)NN * 4);
  int* OFFS   = (int*)alloc((size_t)(NN + 1) * 4);
  int* BLKC   = (int*)alloc((size_t)NCB2 * 4);
  int* INCL   = (int*)alloc((size_t)NCB2 * 4);
  int* BSUM   = (int*)alloc(512 * 4);
  int* BPRE   = (int*)alloc(512 * 4);
  int* PKD    = (int*)alloc((size_t)E * 4);
  unsigned char* PKS = (unsigned char*)alloc((size_t)E);
  int2* EPK   = (int2*)alloc((size_t)E * 8);

  const int chunk = (E + NBLK - 1) / NBLK;
  const int nsa = (NCB2 + 1023) / 1024;

  k_p1<<<NBLK, 256, 0, stream>>>(src, dst, BLKC, E, chunk);
  k_scan_a<<<nsa, 256, 0, stream>>>(BLKC, INCL, BSUM, NCB2);
  k_scan_b<<<1, 512, 0, stream>>>(BSUM, BPRE, nsa);
  k_p2<<<NBLK, 256, 0, stream>>>(src, dst, INCL, BPRE, PKD, PKS, E, chunk);
  k_p3s<<<NC, 256, 0, stream>>>(INCL, BPRE, PKS, DINV, E);
  k_p3d<<<NC, 256, 0, stream>>>(INCL, BPRE, PKD, DINV, OFFS, EPK, E);

  k_wt<<<(HID * KPAD + NPADOUT * HID + 255) / 256, 256, 0, stream>>>(W1, W2, W1T, W2T);

  k_mlp<<<(NN + 127) / 128, 512, 0, stream>>>(X, W1T, B1, W2T, B2, TEMP, X0B, HIDB);

  const int PB = (NN + 15) / 16;
  for (int k = 0; k < 5; k++) {
    k_prop<<<PB, 256, 0, stream>>>(OFFS, EPK, X0B, X1B, HIDB, TEMP, -1);
    k_prop<<<PB, 256, 0, stream>>>(OFFS, EPK, X1B, X0B, HIDB, TEMP, k + 1);
  }
  k_lsm<<<(NN + 3) / 4, 256, 0, stream>>>(HIDB, (float*)d_out);
}